// Round 1
// baseline (39.842 us; speedup 1.0000x reference)
//
#include <hip/hip_runtime.h>
#include <math.h>

#define BB 8
#define NN 2048
#define NVARS 64
#define HH 32
#define DIN 35   // 3 + H

// ---------------- Kernel 1: per-observation MLP -> spike_raw ----------------
__global__ __launch_bounds__(256) void mlp_kernel(
    const float* __restrict__ value, const float* __restrict__ time_norm,
    const float* __restrict__ mask,  const int*   __restrict__ var_id,
    const float* __restrict__ var_emb,
    const float* __restrict__ W1, const float* __restrict__ b1,
    const float* __restrict__ W2, const float* __restrict__ b2,
    const float* __restrict__ gate_w, const float* __restrict__ gate_b,
    float* __restrict__ spike_raw)
{
    __shared__ float sW1[DIN * HH];
    __shared__ float sW2[HH * HH];
    __shared__ float sb1[HH], sb2[HH], sgw[HH];

    const int tid = threadIdx.x;
    for (int i = tid; i < DIN * HH; i += 256) sW1[i] = W1[i];
    for (int i = tid; i < HH * HH;  i += 256) sW2[i] = W2[i];
    if (tid < HH) { sb1[tid] = b1[tid]; sb2[tid] = b2[tid]; sgw[tid] = gate_w[tid]; }
    __syncthreads();

    const int idx = blockIdx.x * 256 + tid;
    if (idx >= BB * NN) return;

    const float mk = mask[idx];
    const float f0 = value[idx] * mk;
    const float f1 = time_norm[idx];
    const int  vid = var_id[idx];

    float ve[HH];
    #pragma unroll
    for (int k = 0; k < HH; ++k) ve[k] = var_emb[vid * HH + k];

    float g1[HH];
    #pragma unroll
    for (int j = 0; j < HH; ++j) {
        float acc = sb1[j] + f0 * sW1[0 * HH + j] + f1 * sW1[1 * HH + j] + mk * sW1[2 * HH + j];
        #pragma unroll
        for (int k = 0; k < HH; ++k) acc += ve[k] * sW1[(3 + k) * HH + j];
        // exact GELU: 0.5 x (1 + erf(x/sqrt(2)))
        g1[j] = 0.5f * acc * (1.0f + erff(acc * 0.70710678118654752f));
    }

    float gate = gate_b[0];
    #pragma unroll
    for (int j = 0; j < HH; ++j) {
        float acc = sb2[j];
        #pragma unroll
        for (int k = 0; k < HH; ++k) acc += g1[k] * sW2[k * HH + j];
        gate += acc * sgw[j];
    }

    const float s = 1.0f / (1.0f + __expf(-gate));
    spike_raw[idx] = s * mk;
}

// ------------- Kernel 2: refractory pairwise sum + epilogue -----------------
// One 64-lane wave per output row (b,n); 4 waves per 256-thread block.
__global__ __launch_bounds__(256) void refr_kernel(
    const float* __restrict__ time_norm, const int* __restrict__ var_id,
    const float* __restrict__ spike_raw,
    const float* __restrict__ log_tau_r, const float* __restrict__ log_alpha,
    float* __restrict__ out)
{
    const int lane = threadIdx.x & 63;
    const int wid  = threadIdx.x >> 6;                 // 0..3
    const int row  = blockIdx.x * 4 + wid;             // [0, B*N)
    const int b    = row / NN;
    const int n    = row - b * NN;
    const int base = b * NN;

    const float t_n  = time_norm[base + n];
    const int   v_n  = var_id[base + n];
    const float sr_n = spike_raw[base + n];

    const float tau     = __expf(log_tau_r[v_n]);
    const float inv_tau = 1.0f / fmaxf(tau, 1e-6f);
    const float alpha   = __expf(log_alpha[v_n]);

    float acc = 0.0f;
    #pragma unroll 4
    for (int m = lane; m < NN; m += 64) {
        const float t_m = time_norm[base + m];
        const int   v_m = var_id[base + m];
        const float sr  = spike_raw[base + m];
        const float td  = t_n - t_m;
        // earlier (td>0) & same variable; spike_raw already carries mask[m],
        // mask[n] is carried by sr_n in the epilogue.
        const float c = (v_m == v_n && td > 0.0f) ? sr * __expf(-td * inv_tau) : 0.0f;
        acc += c;
    }

    // full-wave butterfly reduce (64 lanes)
    #pragma unroll
    for (int off = 32; off > 0; off >>= 1) acc += __shfl_xor(acc, off, 64);

    if (lane == 0) {
        const float inhibit = tanhf(alpha * acc);
        out[base + n] = sr_n * (1.0f - inhibit);   // FLOOR = 0
    }
}

extern "C" void kernel_launch(void* const* d_in, const int* in_sizes, int n_in,
                              void* d_out, int out_size, void* d_ws, size_t ws_size,
                              hipStream_t stream) {
    const float* value     = (const float*)d_in[0];
    const float* time_norm = (const float*)d_in[1];
    const float* mask      = (const float*)d_in[2];
    const int*   var_id    = (const int*)  d_in[3];
    const float* var_emb   = (const float*)d_in[4];
    const float* W1        = (const float*)d_in[5];
    const float* b1        = (const float*)d_in[6];
    const float* W2        = (const float*)d_in[7];
    const float* b2        = (const float*)d_in[8];
    const float* gate_w    = (const float*)d_in[9];
    const float* gate_b    = (const float*)d_in[10];
    const float* log_tau_r = (const float*)d_in[11];
    const float* log_alpha = (const float*)d_in[12];

    float* out       = (float*)d_out;
    float* spike_raw = (float*)d_ws;   // B*N floats = 64 KB, fully rewritten each call

    hipLaunchKernelGGL(mlp_kernel, dim3((BB * NN) / 256), dim3(256), 0, stream,
                       value, time_norm, mask, var_id, var_emb,
                       W1, b1, W2, b2, gate_w, gate_b, spike_raw);

    hipLaunchKernelGGL(refr_kernel, dim3((BB * NN) / 4), dim3(256), 0, stream,
                       time_norm, var_id, spike_raw, log_tau_r, log_alpha, out);
}

// Round 2
// 20.071 us; speedup vs baseline: 1.9850x; 1.9850x over previous
//
#include <hip/hip_runtime.h>
#include <math.h>

#define BB 8
#define NN 2048
#define NVARS 64
#define HH 32

// ---------------- Kernel 1: per-observation MLP -> spike_raw ----------------
// Algebraic collapse:
//   layer1 pre-act = base1[vid] + f0*W1[0,:] + f1*W1[1,:] + mk*W1[2,:]
//     where base1[v] = b1 + sum_k var_emb[v,k]*W1[3+k,:]   (per-var, precomputed)
//   gate = sum_j GELU(pre_j)*w2g[j] + c
//     where w2g = W2 @ gate_w,  c = b2 . gate_w + gate_b
__global__ __launch_bounds__(256) void mlp_kernel(
    const float* __restrict__ value, const float* __restrict__ time_norm,
    const float* __restrict__ mask,  const int*   __restrict__ var_id,
    const float* __restrict__ var_emb,
    const float* __restrict__ W1, const float* __restrict__ b1,
    const float* __restrict__ W2, const float* __restrict__ b2,
    const float* __restrict__ gate_w, const float* __restrict__ gate_b,
    float* __restrict__ spike_raw)
{
    __shared__ float s_base1[NVARS][HH + 1];   // +1 pad: vid-indexed rows, avoid bank conflict
    __shared__ float s_w1v[HH], s_w1t[HH], s_w1m[HH], s_w2g[HH];
    __shared__ float s_c;

    const int tid = threadIdx.x;

    // --- per-block precompute (cheap: ~70K MAC over 256 threads) ---
    for (int e = tid; e < NVARS * HH; e += 256) {
        const int v = e >> 5, j = e & 31;
        float acc = b1[j];
        #pragma unroll
        for (int k = 0; k < HH; ++k) acc += var_emb[v * HH + k] * W1[(3 + k) * HH + j];
        s_base1[v][j] = acc;
    }
    if (tid < HH) {
        s_w1v[tid] = W1[0 * HH + tid];
        s_w1t[tid] = W1[1 * HH + tid];
        s_w1m[tid] = W1[2 * HH + tid];
        float acc = 0.0f;
        #pragma unroll
        for (int j = 0; j < HH; ++j) acc += W2[tid * HH + j] * gate_w[j];
        s_w2g[tid] = acc;
    }
    if (tid == 0) {
        float acc = gate_b[0];
        #pragma unroll
        for (int j = 0; j < HH; ++j) acc += b2[j] * gate_w[j];
        s_c = acc;
    }
    __syncthreads();

    const int idx = blockIdx.x * 256 + tid;
    if (idx >= BB * NN) return;

    const float mk = mask[idx];
    const float f0 = value[idx] * mk;
    const float f1 = time_norm[idx];
    const int  vid = var_id[idx];

    float gate = s_c;
    #pragma unroll
    for (int j = 0; j < HH; ++j) {
        const float pre = s_base1[vid][j] + f0 * s_w1v[j] + f1 * s_w1t[j] + mk * s_w1m[j];
        const float g = 0.5f * pre * (1.0f + erff(pre * 0.70710678118654752f));
        gate = fmaf(g, s_w2g[j], gate);
    }
    spike_raw[idx] = mk / (1.0f + __expf(-gate));
}

// ------------- Kernel 2: bucketed refractory + epilogue -----------------
// One block per (batch, var). Pairs only interact when var matches, so
// gather the ~N/64 matching obs into LDS, then all-pairs within the bucket.
__global__ __launch_bounds__(256) void refr_kernel(
    const float* __restrict__ time_norm, const int* __restrict__ var_id,
    const float* __restrict__ spike_raw,
    const float* __restrict__ log_tau_r, const float* __restrict__ log_alpha,
    float* __restrict__ out)
{
    __shared__ float s_t[NN];
    __shared__ float s_sr[NN];
    __shared__ int   s_idx[NN];
    __shared__ int   s_cnt;

    const int b    = blockIdx.x >> 6;
    const int var  = blockIdx.x & 63;
    const int base = b * NN;
    const int tid  = threadIdx.x;

    if (tid == 0) s_cnt = 0;
    __syncthreads();

    // scan the batch row, vectorized x4, append matches (order irrelevant:
    // strict t_m < t_n makes the pair sum order-independent)
    for (int i0 = tid * 4; i0 < NN; i0 += 256 * 4) {
        const int4   v  = *reinterpret_cast<const int4*>(var_id + base + i0);
        const float4 t  = *reinterpret_cast<const float4*>(time_norm + base + i0);
        const float4 sr = *reinterpret_cast<const float4*>(spike_raw + base + i0);
        if (v.x == var) { int p = atomicAdd(&s_cnt, 1); s_t[p] = t.x; s_sr[p] = sr.x; s_idx[p] = i0 + 0; }
        if (v.y == var) { int p = atomicAdd(&s_cnt, 1); s_t[p] = t.y; s_sr[p] = sr.y; s_idx[p] = i0 + 1; }
        if (v.z == var) { int p = atomicAdd(&s_cnt, 1); s_t[p] = t.z; s_sr[p] = sr.z; s_idx[p] = i0 + 2; }
        if (v.w == var) { int p = atomicAdd(&s_cnt, 1); s_t[p] = t.w; s_sr[p] = sr.w; s_idx[p] = i0 + 3; }
    }
    __syncthreads();

    const int S = s_cnt;
    const float inv_tau = 1.0f / fmaxf(__expf(log_tau_r[var]), 1e-6f);
    const float alpha   = __expf(log_alpha[var]);

    for (int n = tid; n < S; n += 256) {
        const float t_n = s_t[n];
        float acc = 0.0f;
        for (int m = 0; m < S; ++m) {              // LDS broadcast reads
            const float td = t_n - s_t[m];
            acc += (td > 0.0f) ? s_sr[m] * __expf(-td * inv_tau) : 0.0f;
        }
        out[base + s_idx[n]] = s_sr[n] * (1.0f - tanhf(alpha * acc));   // FLOOR=0
    }
}

extern "C" void kernel_launch(void* const* d_in, const int* in_sizes, int n_in,
                              void* d_out, int out_size, void* d_ws, size_t ws_size,
                              hipStream_t stream) {
    const float* value     = (const float*)d_in[0];
    const float* time_norm = (const float*)d_in[1];
    const float* mask      = (const float*)d_in[2];
    const int*   var_id    = (const int*)  d_in[3];
    const float* var_emb   = (const float*)d_in[4];
    const float* W1        = (const float*)d_in[5];
    const float* b1        = (const float*)d_in[6];
    const float* W2        = (const float*)d_in[7];
    const float* b2        = (const float*)d_in[8];
    const float* gate_w    = (const float*)d_in[9];
    const float* gate_b    = (const float*)d_in[10];
    const float* log_tau_r = (const float*)d_in[11];
    const float* log_alpha = (const float*)d_in[12];

    float* out       = (float*)d_out;
    float* spike_raw = (float*)d_ws;   // B*N floats = 64 KB, fully rewritten each call

    hipLaunchKernelGGL(mlp_kernel, dim3((BB * NN) / 256), dim3(256), 0, stream,
                       value, time_norm, mask, var_id, var_emb,
                       W1, b1, W2, b2, gate_w, gate_b, spike_raw);

    hipLaunchKernelGGL(refr_kernel, dim3(BB * NVARS), dim3(256), 0, stream,
                       time_norm, var_id, spike_raw, log_tau_r, log_alpha, out);
}